// Round 18
// baseline (209.807 us; speedup 1.0000x reference)
//
#include <hip/hip_runtime.h>
#include <hip/hip_bf16.h>

#define NH 16
#define DK 64
#define SEQ 2048
#define DMODEL 1024
#define BATCH 2
#define MROWS (BATCH * SEQ) /* 4096 */

using bf16x8 = __attribute__((ext_vector_type(8))) short;
using f32x4  = __attribute__((ext_vector_type(4))) float;

#define NEGI (-1e30f)
#define QSCALE 0.18033688f  /* 0.125 * log2(e): folds 1/sqrt(dk) and exp->exp2 */

static __device__ __forceinline__ unsigned short f2bf(float x) {
  unsigned u = __builtin_bit_cast(unsigned, x);
  u += 0x7fffu + ((u >> 16) & 1u);   // RNE
  return (unsigned short)(u >> 16);
}
// packed f32x2 -> bf16x2 (lo = a, hi = b), single VALU inst, RNE
static __device__ __forceinline__ unsigned cvtpk(float a, float b) {
  unsigned r;
  asm("v_cvt_pk_bf16_f32 %0, %1, %2" : "=v"(r) : "v"(a), "v"(b));
  return r;
}

// ---------------------------------------------------------------- pack mask
__global__ __launch_bounds__(256) void pack_mask(const int* __restrict__ mask,
                                                 unsigned long long* __restrict__ pm,
                                                 int nwords) {
  int wid  = (blockIdx.x * blockDim.x + threadIdx.x) >> 6;
  int lane = threadIdx.x & 63;
  int nw   = (gridDim.x * blockDim.x) >> 6;
  for (int w = wid; w < nwords; w += nw) {
    int v = mask[(long)w * 64 + lane];
    unsigned long long b = __ballot(v != 0);
    if (lane == 0) pm[w] = b;
  }
}

// ---------------------------------------------------------------- GEMM core
// C = (A @ W^T + bias) * cscale.  Proven 2-barrier skeleton, BK=64.
// AF32/WF32: source dtype flags; f32 sources are converted to bf16 IN the
// staging phase (cvt_pk RNE — numerically identical to the old convert pass).
// mode 0: row-major f32.  mode 1: bf16 scatter [B,H,S,dk].
// mode 2: bf16 scatter-transposed [B,H,dk,S] with packed 8B stores.
#define BK 64
#define LDA2 72   // padded LDS row (elems): 144 B, 16B-aligned

template <int AF32, int WF32>
static __device__ __forceinline__ void gemm_body(const void* __restrict__ Avp,
                                                 const void* __restrict__ Wvp,
                                                 const float* __restrict__ bias,
                                                 void* __restrict__ Cv,
                                                 int mode, float cscale, int bid,
                                                 unsigned short* Al, unsigned short* Bl) {
  const int t    = threadIdx.x;
  const int lane = t & 63;
  const int w    = t >> 6;
  const int wm   = w >> 1, wn = w & 1;
  const int g    = lane >> 4, lr = lane & 15;
  const int nb   = bid & 7;
  const int mb   = bid >> 3;
  const long Abase = (long)mb * 128 * 1024;
  const long Wbase = (long)nb * 128 * 1024;

  f32x4 acc[4][4] = {};

  for (int kt = 0; kt < 1024; kt += BK) {
    __syncthreads();
#pragma unroll
    for (int q = 0; q < 4; ++q) {   // stage 128x64 of A and W
      int id  = q * 256 + t;
      int row = id >> 3;            // 0..127
      int c8  = (id & 7) << 3;      // 0..56
      bf16x8 va, vb;
      if (AF32) {
        const float* ap = (const float*)Avp + Abase + (long)row * 1024 + kt + c8;
        float4 x = *(const float4*)ap;
        float4 y = *(const float4*)(ap + 4);
        uint4 u = {cvtpk(x.x, x.y), cvtpk(x.z, x.w), cvtpk(y.x, y.y), cvtpk(y.z, y.w)};
        va = __builtin_bit_cast(bf16x8, u);
      } else {
        va = *(const bf16x8*)((const unsigned short*)Avp + Abase + (long)row * 1024 + kt + c8);
      }
      if (WF32) {
        const float* wp = (const float*)Wvp + Wbase + (long)row * 1024 + kt + c8;
        float4 x = *(const float4*)wp;
        float4 y = *(const float4*)(wp + 4);
        uint4 u = {cvtpk(x.x, x.y), cvtpk(x.z, x.w), cvtpk(y.x, y.y), cvtpk(y.z, y.w)};
        vb = __builtin_bit_cast(bf16x8, u);
      } else {
        vb = *(const bf16x8*)((const unsigned short*)Wvp + Wbase + (long)row * 1024 + kt + c8);
      }
      *(bf16x8*)(&Al[row * LDA2 + c8]) = va;
      *(bf16x8*)(&Bl[row * LDA2 + c8]) = vb;
    }
    __syncthreads();
#pragma unroll
    for (int kh = 0; kh < 2; ++kh) {   // two k=32 halves per staged tile
      bf16x8 af[4], bfr[4];
#pragma unroll
      for (int i = 0; i < 4; ++i) {
        af[i]  = *(const bf16x8*)(&Al[(wm * 64 + i * 16 + lr) * LDA2 + kh * 32 + g * 8]);
        bfr[i] = *(const bf16x8*)(&Bl[(wn * 64 + i * 16 + lr) * LDA2 + kh * 32 + g * 8]);
      }
#pragma unroll
      for (int i = 0; i < 4; ++i)
#pragma unroll
        for (int j = 0; j < 4; ++j)
          acc[i][j] = __builtin_amdgcn_mfma_f32_16x16x32_bf16(af[i], bfr[j], acc[i][j], 0, 0, 0);
    }
  }

#pragma unroll
  for (int j = 0; j < 4; ++j) {
    int n = nb * 128 + wn * 64 + j * 16 + lr;
    float bv = bias[n];
#pragma unroll
    for (int i = 0; i < 4; ++i) {
      int m0 = mb * 128 + wm * 64 + i * 16 + g * 4;
      float v0 = (acc[i][j][0] + bv) * cscale;
      float v1 = (acc[i][j][1] + bv) * cscale;
      float v2 = (acc[i][j][2] + bv) * cscale;
      float v3 = (acc[i][j][3] + bv) * cscale;
      if (mode == 2) {            // V^T: [B,H,dk,S]; 4 consecutive s -> 8B store
        int b = m0 >> 11, s0 = m0 & (SEQ - 1);
        int h = n >> 6, d = n & (DK - 1);
        uint2 pk;
        pk.x = (unsigned)f2bf(v0) | ((unsigned)f2bf(v1) << 16);
        pk.y = (unsigned)f2bf(v2) | ((unsigned)f2bf(v3) << 16);
        *(uint2*)(&((unsigned short*)Cv)[((long)(b * NH + h) * DK + d) * SEQ + s0]) = pk;
      } else if (mode == 1) {     // [B,H,S,dk]
        int b = m0 >> 11, s0 = m0 & (SEQ - 1);
        int h = n >> 6, d = n & (DK - 1);
        unsigned short* p = &((unsigned short*)Cv)[(((long)(b * NH + h) * SEQ + s0) << 6) + d];
        p[0] = f2bf(v0); p[64] = f2bf(v1); p[128] = f2bf(v2); p[192] = f2bf(v3);
      } else {                    // row-major f32
        float* p = &((float*)Cv)[(long)m0 * DMODEL + n];
        p[0] = v0; p[DMODEL] = v1; p[2 * DMODEL] = v2; p[3 * DMODEL] = v3;
      }
    }
  }
}

// merged Q/K/V projection from RAW f32 inputs: 768 blocks, which = bid >> 8
__global__ __launch_bounds__(256) void qkv_proj(const float* __restrict__ Aq,
                                                const float* __restrict__ Ak,
                                                const float* __restrict__ Av,
                                                const float* __restrict__ Wq,
                                                const float* __restrict__ Wk,
                                                const float* __restrict__ Wv,
                                                const float* __restrict__ bq,
                                                const float* __restrict__ bk,
                                                const float* __restrict__ bv,
                                                unsigned short* __restrict__ Cq,
                                                unsigned short* __restrict__ Ck,
                                                unsigned short* __restrict__ Cv) {
  __shared__ unsigned short Al[128 * LDA2];
  __shared__ unsigned short Bl[128 * LDA2];
  int which = blockIdx.x >> 8;
  int bid   = blockIdx.x & 255;
  const float* A = which == 0 ? Aq : (which == 1 ? Ak : Av);
  const float* W = which == 0 ? Wq : (which == 1 ? Wk : Wv);
  const float* b = which == 0 ? bq : (which == 1 ? bk : bv);
  unsigned short* C = which == 0 ? Cq : (which == 1 ? Ck : Cv);
  int   mode  = which == 2 ? 2 : 1;
  float scale = which == 0 ? QSCALE : 1.0f;
  gemm_body<1, 1>(A, W, b, C, mode, scale, bid, Al, Bl);
}

__global__ __launch_bounds__(256) void gemm_out(const unsigned short* __restrict__ A,
                                                const float* __restrict__ W,
                                                const float* __restrict__ bias,
                                                float* __restrict__ C) {
  __shared__ unsigned short Al[128 * LDA2];
  __shared__ unsigned short Bl[128 * LDA2];
  gemm_body<0, 1>(A, W, bias, C, 0, 1.0f, blockIdx.x, Al, Bl);
}

// ---------------------------------------------------------------- attention
// r17 compute kernel (validated incl. replays, XCD-swizzled), with ONE change:
// the P-fence __syncthreads is replaced by a within-wave fence (Pl[w] is
// per-wave private; Vt ordering is covered by the staging barrier; the next
// iteration's top barrier still guards Kl/Vt overwrite). Fence pattern
// validated under replay in r15 (rule #18: lgkmcnt + sched_barrier).
#define KVB 64
#define LD 72

__global__ __launch_bounds__(256) void attn(const unsigned short* __restrict__ Q,
                                            const unsigned short* __restrict__ K,
                                            const unsigned short* __restrict__ VT,
                                            const unsigned long long* __restrict__ pm,
                                            unsigned short* __restrict__ O) {
  __shared__ unsigned short Kl[KVB * LD];
  __shared__ unsigned short Vt[DK * LD];       // Vt[d][kv]
  __shared__ unsigned short Pl[4][32 * LD];    // per-wave 32 q-rows (private)
  const int t    = threadIdx.x;
  const int lane = t & 63;
  const int w    = t >> 6;
  const int g    = lane >> 4, lr = lane & 15;
  const int bh   = blockIdx.x & 31;            // XCD swizzle: bh = id % 32
  const int qb   = blockIdx.x >> 5;            // 0..15
  const int b    = bh >> 4, h = bh & 15;
  const long base = (long)bh * SEQ * DK;       // same flat size for K and VT
  const int q0   = qb * 128 + w * 32;          // wave's first q-row

  // Q fragments: qf[qh][kh] (B-operand of swapped QK^T)
  bf16x8 qf[2][2];
#pragma unroll
  for (int qh = 0; qh < 2; ++qh) {
    const unsigned short* qp = Q + base + (long)(q0 + qh * 16 + lr) * DK;
    qf[qh][0] = *(const bf16x8*)(qp + g * 8);
    qf[qh][1] = *(const bf16x8*)(qp + 32 + g * 8);
  }
  float mrun[2] = {NEGI, NEGI}, lrun[2] = {0.f, 0.f};  // log2-domain
  f32x4 o[2][4] = {};

  for (int kt = 0; kt < SEQ / KVB; ++kt) {
    const int kvbase = kt * KVB;
    __syncthreads();
    // stage K rows [kv][64] — b128 loads/stores
#pragma unroll
    for (int p = 0; p < 2; ++p) {
      int id  = p * 256 + t;
      int row = id >> 3;
      int c8  = (id & 7) << 3;
      bf16x8 kv8 = *(const bf16x8*)(K + base + (long)(kvbase + row) * DK + c8);
      *(bf16x8*)(&Kl[row * LD + c8]) = kv8;
    }
    // stage V^T rows [d][kv-block] — b128 copies
#pragma unroll
    for (int p = 0; p < 2; ++p) {
      int id  = p * 256 + t;
      int row = id >> 3;
      int c8  = (id & 7) << 3;
      bf16x8 vv = *(const bf16x8*)(VT + base + (long)row * SEQ + kvbase + c8);
      *(bf16x8*)(&Vt[row * LD + c8]) = vv;
    }
    __syncthreads();

    // swapped scores: C[kv][q] for both q-groups; K frags read ONCE
    f32x4 sc[2][4];
#pragma unroll
    for (int c = 0; c < 4; ++c) {
      bf16x8 kf0 = *(const bf16x8*)(&Kl[(c * 16 + lr) * LD + g * 8]);
      bf16x8 kf1 = *(const bf16x8*)(&Kl[(c * 16 + lr) * LD + 32 + g * 8]);
#pragma unroll
      for (int qh = 0; qh < 2; ++qh) {
        f32x4 a = {};
        a = __builtin_amdgcn_mfma_f32_16x16x32_bf16(kf0, qf[qh][0], a, 0, 0, 0);
        a = __builtin_amdgcn_mfma_f32_16x16x32_bf16(kf1, qf[qh][1], a, 0, 0, 0);
        sc[qh][c] = a;
      }
    }

    unsigned short* P = &Pl[w][0];
#pragma unroll
    for (int qh = 0; qh < 2; ++qh) {
      const unsigned long long mw = pm[((long)b * SEQ + q0 + qh * 16 + lr) * 32 + kt];
      float s[4][4];
      float mt = NEGI;
#pragma unroll
      for (int c = 0; c < 4; ++c)
#pragma unroll
        for (int r = 0; r < 4; ++r) {
          int kvi = c * 16 + g * 4 + r;
          float v = ((mw >> kvi) & 1ull) ? sc[qh][c][r] : -1e9f;
          s[c][r] = v;
          mt = fmaxf(mt, v);
        }
      mt = fmaxf(mt, __shfl_xor(mt, 16, 64));
      mt = fmaxf(mt, __shfl_xor(mt, 32, 64));

      int need = __any(mt > mrun[qh] + 5.0f);   // defer-max (T13), log2 units
      float mn = mrun[qh], corr = 1.0f;
      if (need) { mn = fmaxf(mrun[qh], mt); corr = __builtin_amdgcn_exp2f(mrun[qh] - mn); mrun[qh] = mn; }

      float pf[4][4];
      float rs = 0.f;
#pragma unroll
      for (int c = 0; c < 4; ++c)
#pragma unroll
        for (int r = 0; r < 4; ++r) {
          float p_ = __builtin_amdgcn_exp2f(s[c][r] - mn);
          pf[c][r] = p_;
          rs += p_;
        }
      rs += __shfl_xor(rs, 16, 64);
      rs += __shfl_xor(rs, 32, 64);

      if (need) {
        lrun[qh] = lrun[qh] * corr + rs;
#pragma unroll
        for (int r = 0; r < 4; ++r) {
          float cq = __shfl(corr, (lane >> 4) * 4 + r, 64);  // corr of q-row g*4+r
#pragma unroll
          for (int dt = 0; dt < 4; ++dt) o[qh][dt][r] *= cq;
        }
      } else {
        lrun[qh] += rs;
      }

      // P store (A-fragment layout): row q-local = qh*16+lr, kv cols
#pragma unroll
      for (int c = 0; c < 4; ++c) {
        uint2 pk;
        pk.x = cvtpk(pf[c][0], pf[c][1]);
        pk.y = cvtpk(pf[c][2], pf[c][3]);
        *(uint2*)(&P[(qh * 16 + lr) * LD + c * 16 + g * 4]) = pk;
      }
    }
    // within-wave fence (Pl[w] is wave-private): P ds_writes drained, and no
    // hoisting of the PV ds_reads above this point (r15-validated pattern).
    asm volatile("s_waitcnt lgkmcnt(0)" ::: "memory");
    __builtin_amdgcn_sched_barrier(0);

    // PV: V fragments read ONCE, used by both q-groups
#pragma unroll
    for (int c32 = 0; c32 < 2; ++c32) {
      bf16x8 pf0 = *(const bf16x8*)(&P[lr * LD + c32 * 32 + g * 8]);
      bf16x8 pf1 = *(const bf16x8*)(&P[(16 + lr) * LD + c32 * 32 + g * 8]);
#pragma unroll
      for (int dt = 0; dt < 4; ++dt) {
        bf16x8 vf = *(const bf16x8*)(&Vt[(dt * 16 + lr) * LD + c32 * 32 + g * 8]);
        o[0][dt] = __builtin_amdgcn_mfma_f32_16x16x32_bf16(pf0, vf, o[0][dt], 0, 0, 0);
        o[1][dt] = __builtin_amdgcn_mfma_f32_16x16x32_bf16(pf1, vf, o[1][dt], 0, 0, 0);
      }
    }
    // drain the PV ds_reads of P before the next tile's P ds_writes
    asm volatile("s_waitcnt lgkmcnt(0)" ::: "memory");
    __builtin_amdgcn_sched_barrier(0);
  }
#pragma unroll
  for (int qh = 0; qh < 2; ++qh) {
    float inv = 1.0f / lrun[qh];
#pragma unroll
    for (int r = 0; r < 4; ++r) {
      float iq = __shfl(inv, (lane >> 4) * 4 + r, 64);
      int q = q0 + qh * 16 + g * 4 + r;
      unsigned short* op = O + ((long)(b * SEQ + q) * DMODEL) + h * DK;
#pragma unroll
      for (int dt = 0; dt < 4; ++dt) op[dt * 16 + lr] = f2bf(o[qh][dt][r] * iq);
    }
  }
}

// ---------------------------------------------------------------- launch
extern "C" void kernel_launch(void* const* d_in, const int* in_sizes, int n_in,
                              void* d_out, int out_size, void* d_ws, size_t ws_size,
                              hipStream_t stream) {
  const int* maskp = (const int*)d_in[3];
  float* out = (float*)d_out;

  char* ws = (char*)d_ws;
  const long MB = 1 << 20;
  unsigned long long* pm = (unsigned long long*)ws;             // 1 MB
  unsigned short* Qb  = (unsigned short*)(ws + 35 * MB);        // 8 MB each
  unsigned short* Kb  = (unsigned short*)(ws + 43 * MB);
  unsigned short* Vb  = (unsigned short*)(ws + 51 * MB);        // holds V^T
  unsigned short* Ab  = (unsigned short*)(ws + 59 * MB);

  const int nwords = BATCH * SEQ * (SEQ / 64);  // 131072
  pack_mask<<<512, 256, 0, stream>>>(maskp, pm, nwords);

  // projections straight from f32 inputs (conversion fused into staging)
  qkv_proj<<<768, 256, 0, stream>>>((const float*)d_in[0], (const float*)d_in[1],
                                    (const float*)d_in[2],
                                    (const float*)d_in[4], (const float*)d_in[6],
                                    (const float*)d_in[8],
                                    (const float*)d_in[5], (const float*)d_in[7],
                                    (const float*)d_in[9],
                                    Qb, Kb, Vb);

  attn<<<BATCH * NH * (SEQ / 128), 256, 0, stream>>>(Qb, Kb, Vb, pm, Ab);

  gemm_out<<<256, 256, 0, stream>>>(Ab, (const float*)d_in[10],
                                    (const float*)d_in[11], out);
}

// Round 19
// 195.452 us; speedup vs baseline: 1.0734x; 1.0734x over previous
//
#include <hip/hip_runtime.h>
#include <hip/hip_bf16.h>

#define NH 16
#define DK 64
#define SEQ 2048
#define DMODEL 1024
#define BATCH 2
#define MROWS (BATCH * SEQ) /* 4096 */

using bf16x8 = __attribute__((ext_vector_type(8))) short;
using f32x4  = __attribute__((ext_vector_type(4))) float;

#define NEGI (-1e30f)
#define QSCALE 0.18033688f  /* 0.125 * log2(e): folds 1/sqrt(dk) and exp->exp2 */

static __device__ __forceinline__ unsigned short f2bf(float x) {
  unsigned u = __builtin_bit_cast(unsigned, x);
  u += 0x7fffu + ((u >> 16) & 1u);   // RNE
  return (unsigned short)(u >> 16);
}
static __device__ __forceinline__ float bf2f(unsigned short h) {
  unsigned u = ((unsigned)h) << 16;
  return __builtin_bit_cast(float, u);
}
// packed f32x2 -> bf16x2 (lo = a, hi = b), single VALU inst
static __device__ __forceinline__ unsigned cvtpk(float a, float b) {
  unsigned r;
  asm("v_cvt_pk_bf16_f32 %0, %1, %2" : "=v"(r) : "v"(a), "v"(b));
  return r;
}

// ------------------------------------------------- converts (f32 -> bf16)
__global__ __launch_bounds__(256) void convert3(const float* __restrict__ s0,
                                                const float* __restrict__ s1,
                                                const float* __restrict__ s2,
                                                unsigned short* __restrict__ d0,
                                                unsigned short* __restrict__ d1,
                                                unsigned short* __restrict__ d2,
                                                long n8, int blkseg) {
  int seg = blockIdx.x / blkseg;
  int ib  = blockIdx.x % blkseg;
  const float* s = seg == 0 ? s0 : (seg == 1 ? s1 : s2);
  unsigned short* d = seg == 0 ? d0 : (seg == 1 ? d1 : d2);
  long i0 = (long)ib * blockDim.x + threadIdx.x;
  long stride = (long)blkseg * blockDim.x;
  for (long i = i0; i < n8; i += stride) {
    const float* p = s + i * 8;
    float4 a = *(const float4*)(p);
    float4 b = *(const float4*)(p + 4);
    uint4 u = {cvtpk(a.x, a.y), cvtpk(a.z, a.w), cvtpk(b.x, b.y), cvtpk(b.z, b.w)};
    *(bf16x8*)(d + i * 8) = __builtin_bit_cast(bf16x8, u);
  }
}
__global__ __launch_bounds__(256) void convert4(const float* __restrict__ s0,
                                                const float* __restrict__ s1,
                                                const float* __restrict__ s2,
                                                const float* __restrict__ s3,
                                                unsigned short* __restrict__ d0,
                                                unsigned short* __restrict__ d1,
                                                unsigned short* __restrict__ d2,
                                                unsigned short* __restrict__ d3,
                                                long n8, int blkseg) {
  int seg = blockIdx.x / blkseg;
  int ib  = blockIdx.x % blkseg;
  const float* s = seg == 0 ? s0 : (seg == 1 ? s1 : (seg == 2 ? s2 : s3));
  unsigned short* d = seg == 0 ? d0 : (seg == 1 ? d1 : (seg == 2 ? d2 : d3));
  long i0 = (long)ib * blockDim.x + threadIdx.x;
  long stride = (long)blkseg * blockDim.x;
  for (long i = i0; i < n8; i += stride) {
    const float* p = s + i * 8;
    float4 a = *(const float4*)(p);
    float4 b = *(const float4*)(p + 4);
    uint4 u = {cvtpk(a.x, a.y), cvtpk(a.z, a.w), cvtpk(b.x, b.y), cvtpk(b.z, b.w)};
    *(bf16x8*)(d + i * 8) = __builtin_bit_cast(bf16x8, u);
  }
}

// ---------------------------------------------------------------- pack mask
__global__ __launch_bounds__(256) void pack_mask(const int* __restrict__ mask,
                                                 unsigned long long* __restrict__ pm,
                                                 int nwords) {
  int wid  = (blockIdx.x * blockDim.x + threadIdx.x) >> 6;
  int lane = threadIdx.x & 63;
  int nw   = (gridDim.x * blockDim.x) >> 6;
  for (int w = wid; w < nwords; w += nw) {
    int v = mask[(long)w * 64 + lane];
    unsigned long long b = __ballot(v != 0);
    if (lane == 0) pm[w] = b;
  }
}

// ---------------------------------------------------------------- GEMM core
// C = (A @ W^T + bias) * cscale.  Proven 2-barrier skeleton, BK=64 (r13).
// mode 0: row-major f32.  mode 1: bf16 scatter [B,H,S,dk].
// mode 2: bf16 scatter-transposed [B,H,dk,S] with packed 8B stores.
#define BK 64
#define LDA2 72   // padded LDS row (elems): 144 B, 16B-aligned

static __device__ __forceinline__ void gemm_body(const unsigned short* __restrict__ A,
                                                 const unsigned short* __restrict__ W,
                                                 const unsigned short* __restrict__ bias,
                                                 void* __restrict__ Cv,
                                                 int mode, float cscale, int bid,
                                                 unsigned short* Al, unsigned short* Bl) {
  const int t    = threadIdx.x;
  const int lane = t & 63;
  const int w    = t >> 6;
  const int wm   = w >> 1, wn = w & 1;
  const int g    = lane >> 4, lr = lane & 15;
  const int nb   = bid & 7;
  const int mb   = bid >> 3;
  const long Abase = (long)mb * 128 * 1024;
  const long Wbase = (long)nb * 128 * 1024;

  f32x4 acc[4][4] = {};

  for (int kt = 0; kt < 1024; kt += BK) {
    __syncthreads();
#pragma unroll
    for (int q = 0; q < 4; ++q) {   // stage 128x64 of A and W (vector loads)
      int id  = q * 256 + t;
      int row = id >> 3;            // 0..127
      int c8  = (id & 7) << 3;      // 0..56
      bf16x8 va = *(const bf16x8*)(A + Abase + (long)row * 1024 + kt + c8);
      bf16x8 vb = *(const bf16x8*)(W + Wbase + (long)row * 1024 + kt + c8);
      *(bf16x8*)(&Al[row * LDA2 + c8]) = va;
      *(bf16x8*)(&Bl[row * LDA2 + c8]) = vb;
    }
    __syncthreads();
#pragma unroll
    for (int kh = 0; kh < 2; ++kh) {   // two k=32 halves per staged tile
      bf16x8 af[4], bfr[4];
#pragma unroll
      for (int i = 0; i < 4; ++i) {
        af[i]  = *(const bf16x8*)(&Al[(wm * 64 + i * 16 + lr) * LDA2 + kh * 32 + g * 8]);
        bfr[i] = *(const bf16x8*)(&Bl[(wn * 64 + i * 16 + lr) * LDA2 + kh * 32 + g * 8]);
      }
#pragma unroll
      for (int i = 0; i < 4; ++i)
#pragma unroll
        for (int j = 0; j < 4; ++j)
          acc[i][j] = __builtin_amdgcn_mfma_f32_16x16x32_bf16(af[i], bfr[j], acc[i][j], 0, 0, 0);
    }
  }

#pragma unroll
  for (int j = 0; j < 4; ++j) {
    int n = nb * 128 + wn * 64 + j * 16 + lr;
    float bv = bf2f(bias[n]);
#pragma unroll
    for (int i = 0; i < 4; ++i) {
      int m0 = mb * 128 + wm * 64 + i * 16 + g * 4;
      float v0 = (acc[i][j][0] + bv) * cscale;
      float v1 = (acc[i][j][1] + bv) * cscale;
      float v2 = (acc[i][j][2] + bv) * cscale;
      float v3 = (acc[i][j][3] + bv) * cscale;
      if (mode == 2) {            // V^T: [B,H,dk,S]; 4 consecutive s -> 8B store
        int b = m0 >> 11, s0 = m0 & (SEQ - 1);
        int h = n >> 6, d = n & (DK - 1);
        uint2 pk;
        pk.x = (unsigned)f2bf(v0) | ((unsigned)f2bf(v1) << 16);
        pk.y = (unsigned)f2bf(v2) | ((unsigned)f2bf(v3) << 16);
        *(uint2*)(&((unsigned short*)Cv)[((long)(b * NH + h) * DK + d) * SEQ + s0]) = pk;
      } else if (mode == 1) {     // [B,H,S,dk]
        int b = m0 >> 11, s0 = m0 & (SEQ - 1);
        int h = n >> 6, d = n & (DK - 1);
        unsigned short* p = &((unsigned short*)Cv)[(((long)(b * NH + h) * SEQ + s0) << 6) + d];
        p[0] = f2bf(v0); p[64] = f2bf(v1); p[128] = f2bf(v2); p[192] = f2bf(v3);
      } else {                    // row-major f32
        float* p = &((float*)Cv)[(long)m0 * DMODEL + n];
        p[0] = v0; p[DMODEL] = v1; p[2 * DMODEL] = v2; p[3 * DMODEL] = v3;
      }
    }
  }
}

// merged Q/K/V projection: 768 blocks, which = blockIdx.x >> 8
__global__ __launch_bounds__(256) void qkv_proj(const unsigned short* __restrict__ Aq,
                                                const unsigned short* __restrict__ Ak,
                                                const unsigned short* __restrict__ Av,
                                                const unsigned short* __restrict__ Wq,
                                                const unsigned short* __restrict__ Wk,
                                                const unsigned short* __restrict__ Wv,
                                                const unsigned short* __restrict__ bq,
                                                const unsigned short* __restrict__ bk,
                                                const unsigned short* __restrict__ bv,
                                                unsigned short* __restrict__ Cq,
                                                unsigned short* __restrict__ Ck,
                                                unsigned short* __restrict__ Cv) {
  __shared__ unsigned short Al[128 * LDA2];
  __shared__ unsigned short Bl[128 * LDA2];
  int which = blockIdx.x >> 8;
  int bid   = blockIdx.x & 255;
  const unsigned short* A = which == 0 ? Aq : (which == 1 ? Ak : Av);
  const unsigned short* W = which == 0 ? Wq : (which == 1 ? Wk : Wv);
  const unsigned short* b = which == 0 ? bq : (which == 1 ? bk : bv);
  unsigned short* C = which == 0 ? Cq : (which == 1 ? Ck : Cv);
  int   mode  = which == 2 ? 2 : 1;
  float scale = which == 0 ? QSCALE : 1.0f;
  gemm_body(A, W, b, C, mode, scale, bid, Al, Bl);
}

__global__ __launch_bounds__(256) void gemm_out(const unsigned short* __restrict__ A,
                                                const unsigned short* __restrict__ W,
                                                const unsigned short* __restrict__ bias,
                                                float* __restrict__ C) {
  __shared__ unsigned short Al[128 * LDA2];
  __shared__ unsigned short Bl[128 * LDA2];
  gemm_body(A, W, bias, C, 0, 1.0f, blockIdx.x, Al, Bl);
}

// ---------------------------------------------------------------- attention
// EXACT r18 attn (validated both checks): XCD-swizzled block mapping +
// wave-private P with within-wave fences (2 block barriers per tile).
#define KVB 64
#define LD 72

__global__ __launch_bounds__(256) void attn(const unsigned short* __restrict__ Q,
                                            const unsigned short* __restrict__ K,
                                            const unsigned short* __restrict__ VT,
                                            const unsigned long long* __restrict__ pm,
                                            unsigned short* __restrict__ O) {
  __shared__ unsigned short Kl[KVB * LD];
  __shared__ unsigned short Vt[DK * LD];       // Vt[d][kv]
  __shared__ unsigned short Pl[4][32 * LD];    // per-wave 32 q-rows (private)
  const int t    = threadIdx.x;
  const int lane = t & 63;
  const int w    = t >> 6;
  const int g    = lane >> 4, lr = lane & 15;
  const int bh   = blockIdx.x & 31;            // XCD swizzle: bh = id % 32
  const int qb   = blockIdx.x >> 5;            // 0..15
  const int b    = bh >> 4, h = bh & 15;
  const long base = (long)bh * SEQ * DK;       // same flat size for K and VT
  const int q0   = qb * 128 + w * 32;          // wave's first q-row

  // Q fragments: qf[qh][kh] (B-operand of swapped QK^T)
  bf16x8 qf[2][2];
#pragma unroll
  for (int qh = 0; qh < 2; ++qh) {
    const unsigned short* qp = Q + base + (long)(q0 + qh * 16 + lr) * DK;
    qf[qh][0] = *(const bf16x8*)(qp + g * 8);
    qf[qh][1] = *(const bf16x8*)(qp + 32 + g * 8);
  }
  float mrun[2] = {NEGI, NEGI}, lrun[2] = {0.f, 0.f};  // log2-domain
  f32x4 o[2][4] = {};

  for (int kt = 0; kt < SEQ / KVB; ++kt) {
    const int kvbase = kt * KVB;
    __syncthreads();
    // stage K rows [kv][64] — b128 loads/stores
#pragma unroll
    for (int p = 0; p < 2; ++p) {
      int id  = p * 256 + t;
      int row = id >> 3;
      int c8  = (id & 7) << 3;
      bf16x8 kv8 = *(const bf16x8*)(K + base + (long)(kvbase + row) * DK + c8);
      *(bf16x8*)(&Kl[row * LD + c8]) = kv8;
    }
    // stage V^T rows [d][kv-block] — b128 copies
#pragma unroll
    for (int p = 0; p < 2; ++p) {
      int id  = p * 256 + t;
      int row = id >> 3;
      int c8  = (id & 7) << 3;
      bf16x8 vv = *(const bf16x8*)(VT + base + (long)row * SEQ + kvbase + c8);
      *(bf16x8*)(&Vt[row * LD + c8]) = vv;
    }
    __syncthreads();

    // swapped scores: C[kv][q] for both q-groups; K frags read ONCE
    f32x4 sc[2][4];
#pragma unroll
    for (int c = 0; c < 4; ++c) {
      bf16x8 kf0 = *(const bf16x8*)(&Kl[(c * 16 + lr) * LD + g * 8]);
      bf16x8 kf1 = *(const bf16x8*)(&Kl[(c * 16 + lr) * LD + 32 + g * 8]);
#pragma unroll
      for (int qh = 0; qh < 2; ++qh) {
        f32x4 a = {};
        a = __builtin_amdgcn_mfma_f32_16x16x32_bf16(kf0, qf[qh][0], a, 0, 0, 0);
        a = __builtin_amdgcn_mfma_f32_16x16x32_bf16(kf1, qf[qh][1], a, 0, 0, 0);
        sc[qh][c] = a;
      }
    }

    unsigned short* P = &Pl[w][0];
#pragma unroll
    for (int qh = 0; qh < 2; ++qh) {
      const unsigned long long mw = pm[((long)b * SEQ + q0 + qh * 16 + lr) * 32 + kt];
      float s[4][4];
      float mt = NEGI;
#pragma unroll
      for (int c = 0; c < 4; ++c)
#pragma unroll
        for (int r = 0; r < 4; ++r) {
          int kvi = c * 16 + g * 4 + r;
          float v = ((mw >> kvi) & 1ull) ? sc[qh][c][r] : -1e9f;
          s[c][r] = v;
          mt = fmaxf(mt, v);
        }
      mt = fmaxf(mt, __shfl_xor(mt, 16, 64));
      mt = fmaxf(mt, __shfl_xor(mt, 32, 64));

      int need = __any(mt > mrun[qh] + 5.0f);   // defer-max (T13), log2 units
      float mn = mrun[qh], corr = 1.0f;
      if (need) { mn = fmaxf(mrun[qh], mt); corr = __builtin_amdgcn_exp2f(mrun[qh] - mn); mrun[qh] = mn; }

      float pf[4][4];
      float rs = 0.f;
#pragma unroll
      for (int c = 0; c < 4; ++c)
#pragma unroll
        for (int r = 0; r < 4; ++r) {
          float p_ = __builtin_amdgcn_exp2f(s[c][r] - mn);
          pf[c][r] = p_;
          rs += p_;
        }
      rs += __shfl_xor(rs, 16, 64);
      rs += __shfl_xor(rs, 32, 64);

      if (need) {
        lrun[qh] = lrun[qh] * corr + rs;
#pragma unroll
        for (int r = 0; r < 4; ++r) {
          float cq = __shfl(corr, (lane >> 4) * 4 + r, 64);  // corr of q-row g*4+r
#pragma unroll
          for (int dt = 0; dt < 4; ++dt) o[qh][dt][r] *= cq;
        }
      } else {
        lrun[qh] += rs;
      }

      // P store (A-fragment layout): row q-local = qh*16+lr, kv cols
#pragma unroll
      for (int c = 0; c < 4; ++c) {
        uint2 pk;
        pk.x = cvtpk(pf[c][0], pf[c][1]);
        pk.y = cvtpk(pf[c][2], pf[c][3]);
        *(uint2*)(&P[(qh * 16 + lr) * LD + c * 16 + g * 4]) = pk;
      }
    }
    // within-wave fence (Pl[w] is wave-private): P ds_writes drained, and no
    // hoisting of the PV ds_reads above this point (r15/r18-validated).
    asm volatile("s_waitcnt lgkmcnt(0)" ::: "memory");
    __builtin_amdgcn_sched_barrier(0);

    // PV: V fragments read ONCE, used by both q-groups
#pragma unroll
    for (int c32 = 0; c32 < 2; ++c32) {
      bf16x8 pf0 = *(const bf16x8*)(&P[lr * LD + c32 * 32 + g * 8]);
      bf16x8 pf1 = *(const bf16x8*)(&P[(16 + lr) * LD + c32 * 32 + g * 8]);
#pragma unroll
      for (int dt = 0; dt < 4; ++dt) {
        bf16x8 vf = *(const bf16x8*)(&Vt[(dt * 16 + lr) * LD + c32 * 32 + g * 8]);
        o[0][dt] = __builtin_amdgcn_mfma_f32_16x16x32_bf16(pf0, vf, o[0][dt], 0, 0, 0);
        o[1][dt] = __builtin_amdgcn_mfma_f32_16x16x32_bf16(pf1, vf, o[1][dt], 0, 0, 0);
      }
    }
    // drain the PV ds_reads of P before the next tile's P ds_writes
    asm volatile("s_waitcnt lgkmcnt(0)" ::: "memory");
    __builtin_amdgcn_sched_barrier(0);
  }
#pragma unroll
  for (int qh = 0; qh < 2; ++qh) {
    float inv = 1.0f / lrun[qh];
#pragma unroll
    for (int r = 0; r < 4; ++r) {
      float iq = __shfl(inv, (lane >> 4) * 4 + r, 64);
      int q = q0 + qh * 16 + g * 4 + r;
      unsigned short* op = O + ((long)(b * SEQ + q) * DMODEL) + h * DK;
#pragma unroll
      for (int dt = 0; dt < 4; ++dt) op[dt * 16 + lr] = f2bf(o[qh][dt][r] * iq);
    }
  }
}

// ---------------------------------------------------------------- launch
extern "C" void kernel_launch(void* const* d_in, const int* in_sizes, int n_in,
                              void* d_out, int out_size, void* d_ws, size_t ws_size,
                              hipStream_t stream) {
  const int* maskp = (const int*)d_in[3];
  float* out = (float*)d_out;

  char* ws = (char*)d_ws;
  const long MB = 1 << 20;
  unsigned long long* pm = (unsigned long long*)ws;             // 1 MB
  unsigned short* Qc  = (unsigned short*)(ws + 1 * MB);         // 8 MB each
  unsigned short* Kc  = (unsigned short*)(ws + 9 * MB);
  unsigned short* Vc  = (unsigned short*)(ws + 17 * MB);
  unsigned short* Wqc = (unsigned short*)(ws + 25 * MB);        // 2 MB each
  unsigned short* Wkc = (unsigned short*)(ws + 27 * MB);
  unsigned short* Wvc = (unsigned short*)(ws + 29 * MB);
  unsigned short* Woc = (unsigned short*)(ws + 31 * MB);
  unsigned short* bqc = (unsigned short*)(ws + 33 * MB);        // 2 KB each
  unsigned short* bkc = (unsigned short*)(ws + 33 * MB + 4096);
  unsigned short* bvc = (unsigned short*)(ws + 33 * MB + 8192);
  unsigned short* boc = (unsigned short*)(ws + 33 * MB + 12288);
  unsigned short* Qb  = (unsigned short*)(ws + 35 * MB);        // 8 MB each
  unsigned short* Kb  = (unsigned short*)(ws + 43 * MB);
  unsigned short* Vb  = (unsigned short*)(ws + 51 * MB);        // holds V^T
  unsigned short* Ab  = (unsigned short*)(ws + 59 * MB);

  const long nQKV8 = (long)MROWS * DMODEL / 8;   // 524288
  const long nW8   = (long)DMODEL * DMODEL / 8;  // 131072
  convert3<<<1536, 256, 0, stream>>>((const float*)d_in[0], (const float*)d_in[1],
                                     (const float*)d_in[2], Qc, Kc, Vc, nQKV8, 512);
  convert4<<<512, 256, 0, stream>>>((const float*)d_in[4], (const float*)d_in[6],
                                    (const float*)d_in[8], (const float*)d_in[10],
                                    Wqc, Wkc, Wvc, Woc, nW8, 128);
  convert4<<<4, 256, 0, stream>>>((const float*)d_in[5], (const float*)d_in[7],
                                  (const float*)d_in[9], (const float*)d_in[11],
                                  bqc, bkc, bvc, boc, DMODEL / 8, 1);

  const int nwords = BATCH * SEQ * (SEQ / 64);  // 131072
  pack_mask<<<512, 256, 0, stream>>>(maskp, pm, nwords);

  qkv_proj<<<768, 256, 0, stream>>>(Qc, Kc, Vc, Wqc, Wkc, Wvc,
                                    bqc, bkc, bvc, Qb, Kb, Vb);

  attn<<<BATCH * NH * (SEQ / 128), 256, 0, stream>>>(Qb, Kb, Vb, pm, Ab);

  gemm_out<<<256, 256, 0, stream>>>(Ab, Woc, boc, out);
}

// Round 20
// 192.233 us; speedup vs baseline: 1.0914x; 1.0167x over previous
//
#include <hip/hip_runtime.h>
#include <hip/hip_bf16.h>

#define NH 16
#define DK 64
#define SEQ 2048
#define DMODEL 1024
#define BATCH 2
#define MROWS (BATCH * SEQ) /* 4096 */

using bf16x8 = __attribute__((ext_vector_type(8))) short;
using f32x4  = __attribute__((ext_vector_type(4))) float;

#define NEGI (-1e30f)
#define QSCALE 0.18033688f  /* 0.125 * log2(e): folds 1/sqrt(dk) and exp->exp2 */

static __device__ __forceinline__ unsigned short f2bf(float x) {
  unsigned u = __builtin_bit_cast(unsigned, x);
  u += 0x7fffu + ((u >> 16) & 1u);   // RNE
  return (unsigned short)(u >> 16);
}
static __device__ __forceinline__ float bf2f(unsigned short h) {
  unsigned u = ((unsigned)h) << 16;
  return __builtin_bit_cast(float, u);
}
// packed f32x2 -> bf16x2 (lo = a, hi = b), single VALU inst
static __device__ __forceinline__ unsigned cvtpk(float a, float b) {
  unsigned r;
  asm("v_cvt_pk_bf16_f32 %0, %1, %2" : "=v"(r) : "v"(a), "v"(b));
  return r;
}

// ------------------------------------------------- converts (f32 -> bf16)
__global__ __launch_bounds__(256) void convert3(const float* __restrict__ s0,
                                                const float* __restrict__ s1,
                                                const float* __restrict__ s2,
                                                unsigned short* __restrict__ d0,
                                                unsigned short* __restrict__ d1,
                                                unsigned short* __restrict__ d2,
                                                long n8, int blkseg) {
  int seg = blockIdx.x / blkseg;
  int ib  = blockIdx.x % blkseg;
  const float* s = seg == 0 ? s0 : (seg == 1 ? s1 : s2);
  unsigned short* d = seg == 0 ? d0 : (seg == 1 ? d1 : d2);
  long i0 = (long)ib * blockDim.x + threadIdx.x;
  long stride = (long)blkseg * blockDim.x;
  for (long i = i0; i < n8; i += stride) {
    const float* p = s + i * 8;
    float4 a = *(const float4*)(p);
    float4 b = *(const float4*)(p + 4);
    uint4 u = {cvtpk(a.x, a.y), cvtpk(a.z, a.w), cvtpk(b.x, b.y), cvtpk(b.z, b.w)};
    *(bf16x8*)(d + i * 8) = __builtin_bit_cast(bf16x8, u);
  }
}
__global__ __launch_bounds__(256) void convert4(const float* __restrict__ s0,
                                                const float* __restrict__ s1,
                                                const float* __restrict__ s2,
                                                const float* __restrict__ s3,
                                                unsigned short* __restrict__ d0,
                                                unsigned short* __restrict__ d1,
                                                unsigned short* __restrict__ d2,
                                                unsigned short* __restrict__ d3,
                                                long n8, int blkseg) {
  int seg = blockIdx.x / blkseg;
  int ib  = blockIdx.x % blkseg;
  const float* s = seg == 0 ? s0 : (seg == 1 ? s1 : (seg == 2 ? s2 : s3));
  unsigned short* d = seg == 0 ? d0 : (seg == 1 ? d1 : (seg == 2 ? d2 : d3));
  long i0 = (long)ib * blockDim.x + threadIdx.x;
  long stride = (long)blkseg * blockDim.x;
  for (long i = i0; i < n8; i += stride) {
    const float* p = s + i * 8;
    float4 a = *(const float4*)(p);
    float4 b = *(const float4*)(p + 4);
    uint4 u = {cvtpk(a.x, a.y), cvtpk(a.z, a.w), cvtpk(b.x, b.y), cvtpk(b.z, b.w)};
    *(bf16x8*)(d + i * 8) = __builtin_bit_cast(bf16x8, u);
  }
}

// ---------------------------------------------------------------- pack mask
__global__ __launch_bounds__(256) void pack_mask(const int* __restrict__ mask,
                                                 unsigned long long* __restrict__ pm,
                                                 int nwords) {
  int wid  = (blockIdx.x * blockDim.x + threadIdx.x) >> 6;
  int lane = threadIdx.x & 63;
  int nw   = (gridDim.x * blockDim.x) >> 6;
  for (int w = wid; w < nwords; w += nw) {
    int v = mask[(long)w * 64 + lane];
    unsigned long long b = __ballot(v != 0);
    if (lane == 0) pm[w] = b;
  }
}

// ---------------------------------------------------------------- GEMM core
// C = (A @ W^T + bias) * cscale.  Proven 2-barrier skeleton, BK=64 (r13).
// mode 0: row-major f32.  mode 1: bf16 scatter [B,H,S,dk].
// mode 2: bf16 scatter-transposed [B,H,dk,S] with packed 8B stores.
#define BK 64
#define LDA2 72   // padded LDS row (elems): 144 B, 16B-aligned

static __device__ __forceinline__ void gemm_body(const unsigned short* __restrict__ A,
                                                 const unsigned short* __restrict__ W,
                                                 const unsigned short* __restrict__ bias,
                                                 void* __restrict__ Cv,
                                                 int mode, float cscale, int bid,
                                                 unsigned short* Al, unsigned short* Bl) {
  const int t    = threadIdx.x;
  const int lane = t & 63;
  const int w    = t >> 6;
  const int wm   = w >> 1, wn = w & 1;
  const int g    = lane >> 4, lr = lane & 15;
  const int nb   = bid & 7;
  const int mb   = bid >> 3;
  const long Abase = (long)mb * 128 * 1024;
  const long Wbase = (long)nb * 128 * 1024;

  f32x4 acc[4][4] = {};

  for (int kt = 0; kt < 1024; kt += BK) {
    __syncthreads();
#pragma unroll
    for (int q = 0; q < 4; ++q) {   // stage 128x64 of A and W (vector loads)
      int id  = q * 256 + t;
      int row = id >> 3;            // 0..127
      int c8  = (id & 7) << 3;      // 0..56
      bf16x8 va = *(const bf16x8*)(A + Abase + (long)row * 1024 + kt + c8);
      bf16x8 vb = *(const bf16x8*)(W + Wbase + (long)row * 1024 + kt + c8);
      *(bf16x8*)(&Al[row * LDA2 + c8]) = va;
      *(bf16x8*)(&Bl[row * LDA2 + c8]) = vb;
    }
    __syncthreads();
#pragma unroll
    for (int kh = 0; kh < 2; ++kh) {   // two k=32 halves per staged tile
      bf16x8 af[4], bfr[4];
#pragma unroll
      for (int i = 0; i < 4; ++i) {
        af[i]  = *(const bf16x8*)(&Al[(wm * 64 + i * 16 + lr) * LDA2 + kh * 32 + g * 8]);
        bfr[i] = *(const bf16x8*)(&Bl[(wn * 64 + i * 16 + lr) * LDA2 + kh * 32 + g * 8]);
      }
#pragma unroll
      for (int i = 0; i < 4; ++i)
#pragma unroll
        for (int j = 0; j < 4; ++j)
          acc[i][j] = __builtin_amdgcn_mfma_f32_16x16x32_bf16(af[i], bfr[j], acc[i][j], 0, 0, 0);
    }
  }

#pragma unroll
  for (int j = 0; j < 4; ++j) {
    int n = nb * 128 + wn * 64 + j * 16 + lr;
    float bv = bf2f(bias[n]);
#pragma unroll
    for (int i = 0; i < 4; ++i) {
      int m0 = mb * 128 + wm * 64 + i * 16 + g * 4;
      float v0 = (acc[i][j][0] + bv) * cscale;
      float v1 = (acc[i][j][1] + bv) * cscale;
      float v2 = (acc[i][j][2] + bv) * cscale;
      float v3 = (acc[i][j][3] + bv) * cscale;
      if (mode == 2) {            // V^T: [B,H,dk,S]; 4 consecutive s -> 8B store
        int b = m0 >> 11, s0 = m0 & (SEQ - 1);
        int h = n >> 6, d = n & (DK - 1);
        uint2 pk;
        pk.x = (unsigned)f2bf(v0) | ((unsigned)f2bf(v1) << 16);
        pk.y = (unsigned)f2bf(v2) | ((unsigned)f2bf(v3) << 16);
        *(uint2*)(&((unsigned short*)Cv)[((long)(b * NH + h) * DK + d) * SEQ + s0]) = pk;
      } else if (mode == 1) {     // [B,H,S,dk]
        int b = m0 >> 11, s0 = m0 & (SEQ - 1);
        int h = n >> 6, d = n & (DK - 1);
        unsigned short* p = &((unsigned short*)Cv)[(((long)(b * NH + h) * SEQ + s0) << 6) + d];
        p[0] = f2bf(v0); p[64] = f2bf(v1); p[128] = f2bf(v2); p[192] = f2bf(v3);
      } else {                    // row-major f32
        float* p = &((float*)Cv)[(long)m0 * DMODEL + n];
        p[0] = v0; p[DMODEL] = v1; p[2 * DMODEL] = v2; p[3 * DMODEL] = v3;
      }
    }
  }
}

// merged Q/K/V projection: 768 blocks, which = blockIdx.x >> 8
__global__ __launch_bounds__(256) void qkv_proj(const unsigned short* __restrict__ Aq,
                                                const unsigned short* __restrict__ Ak,
                                                const unsigned short* __restrict__ Av,
                                                const unsigned short* __restrict__ Wq,
                                                const unsigned short* __restrict__ Wk,
                                                const unsigned short* __restrict__ Wv,
                                                const unsigned short* __restrict__ bq,
                                                const unsigned short* __restrict__ bk,
                                                const unsigned short* __restrict__ bv,
                                                unsigned short* __restrict__ Cq,
                                                unsigned short* __restrict__ Ck,
                                                unsigned short* __restrict__ Cv) {
  __shared__ unsigned short Al[128 * LDA2];
  __shared__ unsigned short Bl[128 * LDA2];
  int which = blockIdx.x >> 8;
  int bid   = blockIdx.x & 255;
  const unsigned short* A = which == 0 ? Aq : (which == 1 ? Ak : Av);
  const unsigned short* W = which == 0 ? Wq : (which == 1 ? Wk : Wv);
  const unsigned short* b = which == 0 ? bq : (which == 1 ? bk : bv);
  unsigned short* C = which == 0 ? Cq : (which == 1 ? Ck : Cv);
  int   mode  = which == 2 ? 2 : 1;
  float scale = which == 0 ? QSCALE : 1.0f;
  gemm_body(A, W, b, C, mode, scale, bid, Al, Bl);
}

__global__ __launch_bounds__(256) void gemm_out(const unsigned short* __restrict__ A,
                                                const unsigned short* __restrict__ W,
                                                const unsigned short* __restrict__ bias,
                                                float* __restrict__ C) {
  __shared__ unsigned short Al[128 * LDA2];
  __shared__ unsigned short Bl[128 * LDA2];
  gemm_body(A, W, bias, C, 0, 1.0f, blockIdx.x, Al, Bl);
}

// ---------------------------------------------------------------- attention
// r19 attn (validated both checks: XCD swizzle + wave-private P fences) with
// ONE change: register-prefetch staging. Tile kt+1's global loads are issued
// right after tile kt's LDS writes, so their L2 latency hides under the whole
// compute phase instead of sitting between the two staging barriers.
// (Prefetch alone was never implicated by the r11/r12 bisect — streaming
// softmax was; barrier skeleton here is byte-identical to r19.)
#define KVB 64
#define LD 72

__global__ __launch_bounds__(256) void attn(const unsigned short* __restrict__ Q,
                                            const unsigned short* __restrict__ K,
                                            const unsigned short* __restrict__ VT,
                                            const unsigned long long* __restrict__ pm,
                                            unsigned short* __restrict__ O) {
  __shared__ unsigned short Kl[KVB * LD];
  __shared__ unsigned short Vt[DK * LD];       // Vt[d][kv]
  __shared__ unsigned short Pl[4][32 * LD];    // per-wave 32 q-rows (private)
  const int t    = threadIdx.x;
  const int lane = t & 63;
  const int w    = t >> 6;
  const int g    = lane >> 4, lr = lane & 15;
  const int bh   = blockIdx.x & 31;            // XCD swizzle: bh = id % 32
  const int qb   = blockIdx.x >> 5;            // 0..15
  const int b    = bh >> 4, h = bh & 15;
  const long base = (long)bh * SEQ * DK;       // same flat size for K and VT
  const int q0   = qb * 128 + w * 32;          // wave's first q-row

  // staging geometry (per thread, 2 chunks each for K and V^T)
  const int kr0 = t >> 3,         kc0 = (t & 7) << 3;
  const int kr1 = (256 + t) >> 3, kc1 = kc0;   // rows 32..63 / d 32..63

  // Q fragments: qf[qh][kh] (B-operand of swapped QK^T)
  bf16x8 qf[2][2];
#pragma unroll
  for (int qh = 0; qh < 2; ++qh) {
    const unsigned short* qp = Q + base + (long)(q0 + qh * 16 + lr) * DK;
    qf[qh][0] = *(const bf16x8*)(qp + g * 8);
    qf[qh][1] = *(const bf16x8*)(qp + 32 + g * 8);
  }
  float mrun[2] = {NEGI, NEGI}, lrun[2] = {0.f, 0.f};  // log2-domain
  f32x4 o[2][4] = {};

  // prefetch tile 0 into registers
  bf16x8 kreg0 = *(const bf16x8*)(K + base + (long)kr0 * DK + kc0);
  bf16x8 kreg1 = *(const bf16x8*)(K + base + (long)kr1 * DK + kc1);
  bf16x8 vreg0 = *(const bf16x8*)(VT + base + (long)kr0 * SEQ + kc0);
  bf16x8 vreg1 = *(const bf16x8*)(VT + base + (long)kr1 * SEQ + kc1);

  for (int kt = 0; kt < SEQ / KVB; ++kt) {
    __syncthreads();   // all reads of the previous tile done; LDS reusable
    *(bf16x8*)(&Kl[kr0 * LD + kc0]) = kreg0;
    *(bf16x8*)(&Kl[kr1 * LD + kc1]) = kreg1;
    *(bf16x8*)(&Vt[kr0 * LD + kc0]) = vreg0;
    *(bf16x8*)(&Vt[kr1 * LD + kc1]) = vreg1;
    if (kt + 1 < SEQ / KVB) {     // issue next tile's loads; latency hides
      const int kvb = (kt + 1) * KVB;
      kreg0 = *(const bf16x8*)(K + base + (long)(kvb + kr0) * DK + kc0);
      kreg1 = *(const bf16x8*)(K + base + (long)(kvb + kr1) * DK + kc1);
      vreg0 = *(const bf16x8*)(VT + base + (long)kr0 * SEQ + kvb + kc0);
      vreg1 = *(const bf16x8*)(VT + base + (long)kr1 * SEQ + kvb + kc1);
    }
    __syncthreads();   // tile kt resident in LDS

    // swapped scores: C[kv][q] for both q-groups; K frags read ONCE
    f32x4 sc[2][4];
#pragma unroll
    for (int c = 0; c < 4; ++c) {
      bf16x8 kf0 = *(const bf16x8*)(&Kl[(c * 16 + lr) * LD + g * 8]);
      bf16x8 kf1 = *(const bf16x8*)(&Kl[(c * 16 + lr) * LD + 32 + g * 8]);
#pragma unroll
      for (int qh = 0; qh < 2; ++qh) {
        f32x4 a = {};
        a = __builtin_amdgcn_mfma_f32_16x16x32_bf16(kf0, qf[qh][0], a, 0, 0, 0);
        a = __builtin_amdgcn_mfma_f32_16x16x32_bf16(kf1, qf[qh][1], a, 0, 0, 0);
        sc[qh][c] = a;
      }
    }

    unsigned short* P = &Pl[w][0];
#pragma unroll
    for (int qh = 0; qh < 2; ++qh) {
      const unsigned long long mw = pm[((long)b * SEQ + q0 + qh * 16 + lr) * 32 + kt];
      float s[4][4];
      float mt = NEGI;
#pragma unroll
      for (int c = 0; c < 4; ++c)
#pragma unroll
        for (int r = 0; r < 4; ++r) {
          int kvi = c * 16 + g * 4 + r;
          float v = ((mw >> kvi) & 1ull) ? sc[qh][c][r] : -1e9f;
          s[c][r] = v;
          mt = fmaxf(mt, v);
        }
      mt = fmaxf(mt, __shfl_xor(mt, 16, 64));
      mt = fmaxf(mt, __shfl_xor(mt, 32, 64));

      int need = __any(mt > mrun[qh] + 5.0f);   // defer-max (T13), log2 units
      float mn = mrun[qh], corr = 1.0f;
      if (need) { mn = fmaxf(mrun[qh], mt); corr = __builtin_amdgcn_exp2f(mrun[qh] - mn); mrun[qh] = mn; }

      float pf[4][4];
      float rs = 0.f;
#pragma unroll
      for (int c = 0; c < 4; ++c)
#pragma unroll
        for (int r = 0; r < 4; ++r) {
          float p_ = __builtin_amdgcn_exp2f(s[c][r] - mn);
          pf[c][r] = p_;
          rs += p_;
        }
      rs += __shfl_xor(rs, 16, 64);
      rs += __shfl_xor(rs, 32, 64);

      if (need) {
        lrun[qh] = lrun[qh] * corr + rs;
#pragma unroll
        for (int r = 0; r < 4; ++r) {
          float cq = __shfl(corr, (lane >> 4) * 4 + r, 64);  // corr of q-row g*4+r
#pragma unroll
          for (int dt = 0; dt < 4; ++dt) o[qh][dt][r] *= cq;
        }
      } else {
        lrun[qh] += rs;
      }

      // P store (A-fragment layout): row q-local = qh*16+lr, kv cols
#pragma unroll
      for (int c = 0; c < 4; ++c) {
        uint2 pk;
        pk.x = cvtpk(pf[c][0], pf[c][1]);
        pk.y = cvtpk(pf[c][2], pf[c][3]);
        *(uint2*)(&P[(qh * 16 + lr) * LD + c * 16 + g * 4]) = pk;
      }
    }
    // within-wave fence (Pl[w] is wave-private): P ds_writes drained, and no
    // hoisting of the PV ds_reads above this point (r15/r18/r19-validated).
    asm volatile("s_waitcnt lgkmcnt(0)" ::: "memory");
    __builtin_amdgcn_sched_barrier(0);

    // PV: V fragments read ONCE, used by both q-groups
#pragma unroll
    for (int c32 = 0; c32 < 2; ++c32) {
      bf16x8 pf0 = *(const bf16x8*)(&P[lr * LD + c32 * 32 + g * 8]);
      bf16x8 pf1 = *(const bf16x8*)(&P[(16 + lr) * LD + c32 * 32 + g * 8]);
#pragma unroll
      for (int dt = 0; dt < 4; ++dt) {
        bf16x8 vf = *(const bf16x8*)(&Vt[(dt * 16 + lr) * LD + c32 * 32 + g * 8]);
        o[0][dt] = __builtin_amdgcn_mfma_f32_16x16x32_bf16(pf0, vf, o[0][dt], 0, 0, 0);
        o[1][dt] = __builtin_amdgcn_mfma_f32_16x16x32_bf16(pf1, vf, o[1][dt], 0, 0, 0);
      }
    }
    // drain the PV ds_reads of P before the next tile's P ds_writes
    asm volatile("s_waitcnt lgkmcnt(0)" ::: "memory");
    __builtin_amdgcn_sched_barrier(0);
  }
#pragma unroll
  for (int qh = 0; qh < 2; ++qh) {
    float inv = 1.0f / lrun[qh];
#pragma unroll
    for (int r = 0; r < 4; ++r) {
      float iq = __shfl(inv, (lane >> 4) * 4 + r, 64);
      int q = q0 + qh * 16 + g * 4 + r;
      unsigned short* op = O + ((long)(b * SEQ + q) * DMODEL) + h * DK;
#pragma unroll
      for (int dt = 0; dt < 4; ++dt) op[dt * 16 + lr] = f2bf(o[qh][dt][r] * iq);
    }
  }
}

// ---------------------------------------------------------------- launch
extern "C" void kernel_launch(void* const* d_in, const int* in_sizes, int n_in,
                              void* d_out, int out_size, void* d_ws, size_t ws_size,
                              hipStream_t stream) {
  const int* maskp = (const int*)d_in[3];
  float* out = (float*)d_out;

  char* ws = (char*)d_ws;
  const long MB = 1 << 20;
  unsigned long long* pm = (unsigned long long*)ws;             // 1 MB
  unsigned short* Qc  = (unsigned short*)(ws + 1 * MB);         // 8 MB each
  unsigned short* Kc  = (unsigned short*)(ws + 9 * MB);
  unsigned short* Vc  = (unsigned short*)(ws + 17 * MB);
  unsigned short* Wqc = (unsigned short*)(ws + 25 * MB);        // 2 MB each
  unsigned short* Wkc = (unsigned short*)(ws + 27 * MB);
  unsigned short* Wvc = (unsigned short*)(ws + 29 * MB);
  unsigned short* Woc = (unsigned short*)(ws + 31 * MB);
  unsigned short* bqc = (unsigned short*)(ws + 33 * MB);        // 2 KB each
  unsigned short* bkc = (unsigned short*)(ws + 33 * MB + 4096);
  unsigned short* bvc = (unsigned short*)(ws + 33 * MB + 8192);
  unsigned short* boc = (unsigned short*)(ws + 33 * MB + 12288);
  unsigned short* Qb  = (unsigned short*)(ws + 35 * MB);        // 8 MB each
  unsigned short* Kb  = (unsigned short*)(ws + 43 * MB);
  unsigned short* Vb  = (unsigned short*)(ws + 51 * MB);        // holds V^T
  unsigned short* Ab  = (unsigned short*)(ws + 59 * MB);

  const long nQKV8 = (long)MROWS * DMODEL / 8;   // 524288
  const long nW8   = (long)DMODEL * DMODEL / 8;  // 131072
  convert3<<<1536, 256, 0, stream>>>((const float*)d_in[0], (const float*)d_in[1],
                                     (const float*)d_in[2], Qc, Kc, Vc, nQKV8, 512);
  convert4<<<512, 256, 0, stream>>>((const float*)d_in[4], (const float*)d_in[6],
                                    (const float*)d_in[8], (const float*)d_in[10],
                                    Wqc, Wkc, Wvc, Woc, nW8, 128);
  convert4<<<4, 256, 0, stream>>>((const float*)d_in[5], (const float*)d_in[7],
                                  (const float*)d_in[9], (const float*)d_in[11],
                                  bqc, bkc, bvc, boc, DMODEL / 8, 1);

  const int nwords = BATCH * SEQ * (SEQ / 64);  // 131072
  pack_mask<<<512, 256, 0, stream>>>(maskp, pm, nwords);

  qkv_proj<<<768, 256, 0, stream>>>(Qc, Kc, Vc, Wqc, Wkc, Wvc,
                                    bqc, bkc, bvc, Qb, Kb, Vb);

  attn<<<BATCH * NH * (SEQ / 128), 256, 0, stream>>>(Qb, Kb, Vb, pm, Ab);

  gemm_out<<<256, 256, 0, stream>>>(Ab, Woc, boc, out);
}

// Round 21
// 183.133 us; speedup vs baseline: 1.1457x; 1.0497x over previous
//
#include <hip/hip_runtime.h>
#include <hip/hip_bf16.h>

#define NH 16
#define DK 64
#define SEQ 2048
#define DMODEL 1024
#define BATCH 2
#define MROWS (BATCH * SEQ) /* 4096 */

using bf16x8 = __attribute__((ext_vector_type(8))) short;
using f32x4  = __attribute__((ext_vector_type(4))) float;

#define NEGI (-1e30f)
#define QSCALE 0.18033688f  /* 0.125 * log2(e): folds 1/sqrt(dk) and exp->exp2 */

static __device__ __forceinline__ unsigned short f2bf(float x) {
  unsigned u = __builtin_bit_cast(unsigned, x);
  u += 0x7fffu + ((u >> 16) & 1u);   // RNE
  return (unsigned short)(u >> 16);
}
static __device__ __forceinline__ float bf2f(unsigned short h) {
  unsigned u = ((unsigned)h) << 16;
  return __builtin_bit_cast(float, u);
}
// packed f32x2 -> bf16x2 (lo = a, hi = b), single VALU inst
static __device__ __forceinline__ unsigned cvtpk(float a, float b) {
  unsigned r;
  asm("v_cvt_pk_bf16_f32 %0, %1, %2" : "=v"(r) : "v"(a), "v"(b));
  return r;
}
// async global->LDS, 16B per lane; LDS dest is wave-uniform base + lane*16
static __device__ __forceinline__ void gl_lds16(const unsigned short* g,
                                                unsigned short* l) {
  __builtin_amdgcn_global_load_lds(
      (const __attribute__((address_space(1))) unsigned int*)g,
      (__attribute__((address_space(3))) unsigned int*)l, 16, 0, 0);
}

// ------------------------------------------------- converts (f32 -> bf16)
__global__ __launch_bounds__(256) void convert3(const float* __restrict__ s0,
                                                const float* __restrict__ s1,
                                                const float* __restrict__ s2,
                                                unsigned short* __restrict__ d0,
                                                unsigned short* __restrict__ d1,
                                                unsigned short* __restrict__ d2,
                                                long n8, int blkseg) {
  int seg = blockIdx.x / blkseg;
  int ib  = blockIdx.x % blkseg;
  const float* s = seg == 0 ? s0 : (seg == 1 ? s1 : s2);
  unsigned short* d = seg == 0 ? d0 : (seg == 1 ? d1 : d2);
  long i0 = (long)ib * blockDim.x + threadIdx.x;
  long stride = (long)blkseg * blockDim.x;
  for (long i = i0; i < n8; i += stride) {
    const float* p = s + i * 8;
    float4 a = *(const float4*)(p);
    float4 b = *(const float4*)(p + 4);
    uint4 u = {cvtpk(a.x, a.y), cvtpk(a.z, a.w), cvtpk(b.x, b.y), cvtpk(b.z, b.w)};
    *(bf16x8*)(d + i * 8) = __builtin_bit_cast(bf16x8, u);
  }
}
__global__ __launch_bounds__(256) void convert4(const float* __restrict__ s0,
                                                const float* __restrict__ s1,
                                                const float* __restrict__ s2,
                                                const float* __restrict__ s3,
                                                unsigned short* __restrict__ d0,
                                                unsigned short* __restrict__ d1,
                                                unsigned short* __restrict__ d2,
                                                unsigned short* __restrict__ d3,
                                                long n8, int blkseg) {
  int seg = blockIdx.x / blkseg;
  int ib  = blockIdx.x % blkseg;
  const float* s = seg == 0 ? s0 : (seg == 1 ? s1 : (seg == 2 ? s2 : s3));
  unsigned short* d = seg == 0 ? d0 : (seg == 1 ? d1 : (seg == 2 ? d2 : d3));
  long i0 = (long)ib * blockDim.x + threadIdx.x;
  long stride = (long)blkseg * blockDim.x;
  for (long i = i0; i < n8; i += stride) {
    const float* p = s + i * 8;
    float4 a = *(const float4*)(p);
    float4 b = *(const float4*)(p + 4);
    uint4 u = {cvtpk(a.x, a.y), cvtpk(a.z, a.w), cvtpk(b.x, b.y), cvtpk(b.z, b.w)};
    *(bf16x8*)(d + i * 8) = __builtin_bit_cast(bf16x8, u);
  }
}

// ---------------------------------------------------------------- pack mask
__global__ __launch_bounds__(256) void pack_mask(const int* __restrict__ mask,
                                                 unsigned long long* __restrict__ pm,
                                                 int nwords) {
  int wid  = (blockIdx.x * blockDim.x + threadIdx.x) >> 6;
  int lane = threadIdx.x & 63;
  int nw   = (gridDim.x * blockDim.x) >> 6;
  for (int w = wid; w < nwords; w += nw) {
    int v = mask[(long)w * 64 + lane];
    unsigned long long b = __ballot(v != 0);
    if (lane == 0) pm[w] = b;
  }
}

// ---------------------------------------------------------------- GEMM core
// C = (A @ W^T + bias) * cscale.  m97 structure: BK=32, linear [128][32] LDS,
// global_load_lds(16B) staging. RACE FIX vs r7: explicit s_waitcnt vmcnt(0)
// before the post-staging barrier (the intrinsic's in-flight loads are not
// visibly data-dependent, so the compiler's barrier drain may omit vmcnt).
// mode 0: row-major f32.  mode 1: bf16 scatter [B,H,S,dk].
// mode 2: bf16 scatter-transposed [B,H,dk,S] with packed 8B stores.
#define BK 32

static __device__ __forceinline__ void gemm_body(const unsigned short* __restrict__ A,
                                                 const unsigned short* __restrict__ W,
                                                 const unsigned short* __restrict__ bias,
                                                 void* __restrict__ Cv,
                                                 int mode, float cscale, int bid,
                                                 unsigned short* Al, unsigned short* Bl) {
  const int t    = threadIdx.x;
  const int lane = t & 63;
  const int w    = t >> 6;
  const int wm   = w >> 1, wn = w & 1;
  const int g    = lane >> 4, lr = lane & 15;
  const int nb   = bid & 7;
  const int mb   = bid >> 3;
  const long Abase = (long)mb * 128 * 1024;
  const long Wbase = (long)nb * 128 * 1024;
  // staging geometry: slab = w*2+q covers 16 rows of 32 elems (1 KB linear)
  const int srow = lane >> 2;          // 0..15 within slab
  const int scol = (lane & 3) << 3;    // 0,8,16,24

  f32x4 acc[4][4] = {};

  for (int kt = 0; kt < 1024; kt += BK) {
    __syncthreads();                   // previous tile's reads complete
#pragma unroll
    for (int q = 0; q < 2; ++q) {
      int slab = w * 2 + q;            // 0..7
      int row  = slab * 16 + srow;
      gl_lds16(A + Abase + (long)row * 1024 + kt + scol, Al + slab * 512);
      gl_lds16(W + Wbase + (long)row * 1024 + kt + scol, Bl + slab * 512);
    }
    // RACE FIX: drain this wave's direct-to-LDS loads before the barrier
    asm volatile("s_waitcnt vmcnt(0)" ::: "memory");
    __syncthreads();                   // tile resident for all waves
    bf16x8 af[4], bfr[4];
#pragma unroll
    for (int i = 0; i < 4; ++i) {
      af[i]  = *(const bf16x8*)(&Al[(wm * 64 + i * 16 + lr) * 32 + g * 8]);
      bfr[i] = *(const bf16x8*)(&Bl[(wn * 64 + i * 16 + lr) * 32 + g * 8]);
    }
#pragma unroll
    for (int i = 0; i < 4; ++i)
#pragma unroll
      for (int j = 0; j < 4; ++j)
        acc[i][j] = __builtin_amdgcn_mfma_f32_16x16x32_bf16(af[i], bfr[j], acc[i][j], 0, 0, 0);
  }

#pragma unroll
  for (int j = 0; j < 4; ++j) {
    int n = nb * 128 + wn * 64 + j * 16 + lr;
    float bv = bf2f(bias[n]);
#pragma unroll
    for (int i = 0; i < 4; ++i) {
      int m0 = mb * 128 + wm * 64 + i * 16 + g * 4;
      float v0 = (acc[i][j][0] + bv) * cscale;
      float v1 = (acc[i][j][1] + bv) * cscale;
      float v2 = (acc[i][j][2] + bv) * cscale;
      float v3 = (acc[i][j][3] + bv) * cscale;
      if (mode == 2) {            // V^T: [B,H,dk,S]; 4 consecutive s -> 8B store
        int b = m0 >> 11, s0 = m0 & (SEQ - 1);
        int h = n >> 6, d = n & (DK - 1);
        uint2 pk;
        pk.x = (unsigned)f2bf(v0) | ((unsigned)f2bf(v1) << 16);
        pk.y = (unsigned)f2bf(v2) | ((unsigned)f2bf(v3) << 16);
        *(uint2*)(&((unsigned short*)Cv)[((long)(b * NH + h) * DK + d) * SEQ + s0]) = pk;
      } else if (mode == 1) {     // [B,H,S,dk]
        int b = m0 >> 11, s0 = m0 & (SEQ - 1);
        int h = n >> 6, d = n & (DK - 1);
        unsigned short* p = &((unsigned short*)Cv)[(((long)(b * NH + h) * SEQ + s0) << 6) + d];
        p[0] = f2bf(v0); p[64] = f2bf(v1); p[128] = f2bf(v2); p[192] = f2bf(v3);
      } else {                    // row-major f32
        float* p = &((float*)Cv)[(long)m0 * DMODEL + n];
        p[0] = v0; p[DMODEL] = v1; p[2 * DMODEL] = v2; p[3 * DMODEL] = v3;
      }
    }
  }
}

// merged Q/K/V projection: 768 blocks, which = blockIdx.x >> 8
__global__ __launch_bounds__(256) void qkv_proj(const unsigned short* __restrict__ Aq,
                                                const unsigned short* __restrict__ Ak,
                                                const unsigned short* __restrict__ Av,
                                                const unsigned short* __restrict__ Wq,
                                                const unsigned short* __restrict__ Wk,
                                                const unsigned short* __restrict__ Wv,
                                                const unsigned short* __restrict__ bq,
                                                const unsigned short* __restrict__ bk,
                                                const unsigned short* __restrict__ bv,
                                                unsigned short* __restrict__ Cq,
                                                unsigned short* __restrict__ Ck,
                                                unsigned short* __restrict__ Cv) {
  __shared__ unsigned short Al[128 * 32];
  __shared__ unsigned short Bl[128 * 32];
  int which = blockIdx.x >> 8;
  int bid   = blockIdx.x & 255;
  const unsigned short* A = which == 0 ? Aq : (which == 1 ? Ak : Av);
  const unsigned short* W = which == 0 ? Wq : (which == 1 ? Wk : Wv);
  const unsigned short* b = which == 0 ? bq : (which == 1 ? bk : bv);
  unsigned short* C = which == 0 ? Cq : (which == 1 ? Ck : Cv);
  int   mode  = which == 2 ? 2 : 1;
  float scale = which == 0 ? QSCALE : 1.0f;
  gemm_body(A, W, b, C, mode, scale, bid, Al, Bl);
}

__global__ __launch_bounds__(256) void gemm_out(const unsigned short* __restrict__ A,
                                                const unsigned short* __restrict__ W,
                                                const unsigned short* __restrict__ bias,
                                                float* __restrict__ C) {
  __shared__ unsigned short Al[128 * 32];
  __shared__ unsigned short Bl[128 * 32];
  gemm_body(A, W, bias, C, 0, 1.0f, blockIdx.x, Al, Bl);
}

// ---------------------------------------------------------------- attention
// EXACT r20 attn (validated both checks): XCD swizzle + wave-private P fences
// + register-prefetch staging.
#define KVB 64
#define LD 72

__global__ __launch_bounds__(256) void attn(const unsigned short* __restrict__ Q,
                                            const unsigned short* __restrict__ K,
                                            const unsigned short* __restrict__ VT,
                                            const unsigned long long* __restrict__ pm,
                                            unsigned short* __restrict__ O) {
  __shared__ unsigned short Kl[KVB * LD];
  __shared__ unsigned short Vt[DK * LD];       // Vt[d][kv]
  __shared__ unsigned short Pl[4][32 * LD];    // per-wave 32 q-rows (private)
  const int t    = threadIdx.x;
  const int lane = t & 63;
  const int w    = t >> 6;
  const int g    = lane >> 4, lr = lane & 15;
  const int bh   = blockIdx.x & 31;            // XCD swizzle: bh = id % 32
  const int qb   = blockIdx.x >> 5;            // 0..15
  const int b    = bh >> 4, h = bh & 15;
  const long base = (long)bh * SEQ * DK;       // same flat size for K and VT
  const int q0   = qb * 128 + w * 32;          // wave's first q-row

  // staging geometry (per thread, 2 chunks each for K and V^T)
  const int kr0 = t >> 3,         kc0 = (t & 7) << 3;
  const int kr1 = (256 + t) >> 3, kc1 = kc0;   // rows 32..63 / d 32..63

  // Q fragments: qf[qh][kh] (B-operand of swapped QK^T)
  bf16x8 qf[2][2];
#pragma unroll
  for (int qh = 0; qh < 2; ++qh) {
    const unsigned short* qp = Q + base + (long)(q0 + qh * 16 + lr) * DK;
    qf[qh][0] = *(const bf16x8*)(qp + g * 8);
    qf[qh][1] = *(const bf16x8*)(qp + 32 + g * 8);
  }
  float mrun[2] = {NEGI, NEGI}, lrun[2] = {0.f, 0.f};  // log2-domain
  f32x4 o[2][4] = {};

  // prefetch tile 0 into registers
  bf16x8 kreg0 = *(const bf16x8*)(K + base + (long)kr0 * DK + kc0);
  bf16x8 kreg1 = *(const bf16x8*)(K + base + (long)kr1 * DK + kc1);
  bf16x8 vreg0 = *(const bf16x8*)(VT + base + (long)kr0 * SEQ + kc0);
  bf16x8 vreg1 = *(const bf16x8*)(VT + base + (long)kr1 * SEQ + kc1);

  for (int kt = 0; kt < SEQ / KVB; ++kt) {
    __syncthreads();   // all reads of the previous tile done; LDS reusable
    *(bf16x8*)(&Kl[kr0 * LD + kc0]) = kreg0;
    *(bf16x8*)(&Kl[kr1 * LD + kc1]) = kreg1;
    *(bf16x8*)(&Vt[kr0 * LD + kc0]) = vreg0;
    *(bf16x8*)(&Vt[kr1 * LD + kc1]) = vreg1;
    if (kt + 1 < SEQ / KVB) {     // issue next tile's loads; latency hides
      const int kvb = (kt + 1) * KVB;
      kreg0 = *(const bf16x8*)(K + base + (long)(kvb + kr0) * DK + kc0);
      kreg1 = *(const bf16x8*)(K + base + (long)(kvb + kr1) * DK + kc1);
      vreg0 = *(const bf16x8*)(VT + base + (long)kr0 * SEQ + kvb + kc0);
      vreg1 = *(const bf16x8*)(VT + base + (long)kr1 * SEQ + kvb + kc1);
    }
    __syncthreads();   // tile kt resident in LDS

    // swapped scores: C[kv][q] for both q-groups; K frags read ONCE
    f32x4 sc[2][4];
#pragma unroll
    for (int c = 0; c < 4; ++c) {
      bf16x8 kf0 = *(const bf16x8*)(&Kl[(c * 16 + lr) * LD + g * 8]);
      bf16x8 kf1 = *(const bf16x8*)(&Kl[(c * 16 + lr) * LD + 32 + g * 8]);
#pragma unroll
      for (int qh = 0; qh < 2; ++qh) {
        f32x4 a = {};
        a = __builtin_amdgcn_mfma_f32_16x16x32_bf16(kf0, qf[qh][0], a, 0, 0, 0);
        a = __builtin_amdgcn_mfma_f32_16x16x32_bf16(kf1, qf[qh][1], a, 0, 0, 0);
        sc[qh][c] = a;
      }
    }

    unsigned short* P = &Pl[w][0];
#pragma unroll
    for (int qh = 0; qh < 2; ++qh) {
      const unsigned long long mw = pm[((long)b * SEQ + q0 + qh * 16 + lr) * 32 + kt];
      float s[4][4];
      float mt = NEGI;
#pragma unroll
      for (int c = 0; c < 4; ++c)
#pragma unroll
        for (int r = 0; r < 4; ++r) {
          int kvi = c * 16 + g * 4 + r;
          float v = ((mw >> kvi) & 1ull) ? sc[qh][c][r] : -1e9f;
          s[c][r] = v;
          mt = fmaxf(mt, v);
        }
      mt = fmaxf(mt, __shfl_xor(mt, 16, 64));
      mt = fmaxf(mt, __shfl_xor(mt, 32, 64));

      int need = __any(mt > mrun[qh] + 5.0f);   // defer-max (T13), log2 units
      float mn = mrun[qh], corr = 1.0f;
      if (need) { mn = fmaxf(mrun[qh], mt); corr = __builtin_amdgcn_exp2f(mrun[qh] - mn); mrun[qh] = mn; }

      float pf[4][4];
      float rs = 0.f;
#pragma unroll
      for (int c = 0; c < 4; ++c)
#pragma unroll
        for (int r = 0; r < 4; ++r) {
          float p_ = __builtin_amdgcn_exp2f(s[c][r] - mn);
          pf[c][r] = p_;
          rs += p_;
        }
      rs += __shfl_xor(rs, 16, 64);
      rs += __shfl_xor(rs, 32, 64);

      if (need) {
        lrun[qh] = lrun[qh] * corr + rs;
#pragma unroll
        for (int r = 0; r < 4; ++r) {
          float cq = __shfl(corr, (lane >> 4) * 4 + r, 64);  // corr of q-row g*4+r
#pragma unroll
          for (int dt = 0; dt < 4; ++dt) o[qh][dt][r] *= cq;
        }
      } else {
        lrun[qh] += rs;
      }

      // P store (A-fragment layout): row q-local = qh*16+lr, kv cols
#pragma unroll
      for (int c = 0; c < 4; ++c) {
        uint2 pk;
        pk.x = cvtpk(pf[c][0], pf[c][1]);
        pk.y = cvtpk(pf[c][2], pf[c][3]);
        *(uint2*)(&P[(qh * 16 + lr) * LD + c * 16 + g * 4]) = pk;
      }
    }
    // within-wave fence (Pl[w] is wave-private): P ds_writes drained, and no
    // hoisting of the PV ds_reads above this point (r15/r18/r19-validated).
    asm volatile("s_waitcnt lgkmcnt(0)" ::: "memory");
    __builtin_amdgcn_sched_barrier(0);

    // PV: V fragments read ONCE, used by both q-groups
#pragma unroll
    for (int c32 = 0; c32 < 2; ++c32) {
      bf16x8 pf0 = *(const bf16x8*)(&P[lr * LD + c32 * 32 + g * 8]);
      bf16x8 pf1 = *(const bf16x8*)(&P[(16 + lr) * LD + c32 * 32 + g * 8]);
#pragma unroll
      for (int dt = 0; dt < 4; ++dt) {
        bf16x8 vf = *(const bf16x8*)(&Vt[(dt * 16 + lr) * LD + c32 * 32 + g * 8]);
        o[0][dt] = __builtin_amdgcn_mfma_f32_16x16x32_bf16(pf0, vf, o[0][dt], 0, 0, 0);
        o[1][dt] = __builtin_amdgcn_mfma_f32_16x16x32_bf16(pf1, vf, o[1][dt], 0, 0, 0);
      }
    }
    // drain the PV ds_reads of P before the next tile's P ds_writes
    asm volatile("s_waitcnt lgkmcnt(0)" ::: "memory");
    __builtin_amdgcn_sched_barrier(0);
  }
#pragma unroll
  for (int qh = 0; qh < 2; ++qh) {
    float inv = 1.0f / lrun[qh];
#pragma unroll
    for (int r = 0; r < 4; ++r) {
      float iq = __shfl(inv, (lane >> 4) * 4 + r, 64);
      int q = q0 + qh * 16 + g * 4 + r;
      unsigned short* op = O + ((long)(b * SEQ + q) * DMODEL) + h * DK;
#pragma unroll
      for (int dt = 0; dt < 4; ++dt) op[dt * 16 + lr] = f2bf(o[qh][dt][r] * iq);
    }
  }
}

// ---------------------------------------------------------------- launch
extern "C" void kernel_launch(void* const* d_in, const int* in_sizes, int n_in,
                              void* d_out, int out_size, void* d_ws, size_t ws_size,
                              hipStream_t stream) {
  const int* maskp = (const int*)d_in[3];
  float* out = (float*)d_out;

  char* ws = (char*)d_ws;
  const long MB = 1 << 20;
  unsigned long long* pm = (unsigned long long*)ws;             // 1 MB
  unsigned short* Qc  = (unsigned short*)(ws + 1 * MB);         // 8 MB each
  unsigned short* Kc  = (unsigned short*)(ws + 9 * MB);
  unsigned short* Vc  = (unsigned short*)(ws + 17 * MB);
  unsigned short* Wqc = (unsigned short*)(ws + 25 * MB);        // 2 MB each
  unsigned short* Wkc = (unsigned short*)(ws + 27 * MB);
  unsigned short* Wvc = (unsigned short*)(ws + 29 * MB);
  unsigned short* Woc = (unsigned short*)(ws + 31 * MB);
  unsigned short* bqc = (unsigned short*)(ws + 33 * MB);        // 2 KB each
  unsigned short* bkc = (unsigned short*)(ws + 33 * MB + 4096);
  unsigned short* bvc = (unsigned short*)(ws + 33 * MB + 8192);
  unsigned short* boc = (unsigned short*)(ws + 33 * MB + 12288);
  unsigned short* Qb  = (unsigned short*)(ws + 35 * MB);        // 8 MB each
  unsigned short* Kb  = (unsigned short*)(ws + 43 * MB);
  unsigned short* Vb  = (unsigned short*)(ws + 51 * MB);        // holds V^T
  unsigned short* Ab  = (unsigned short*)(ws + 59 * MB);

  const long nQKV8 = (long)MROWS * DMODEL / 8;   // 524288
  const long nW8   = (long)DMODEL * DMODEL / 8;  // 131072
  convert3<<<1536, 256, 0, stream>>>((const float*)d_in[0], (const float*)d_in[1],
                                     (const float*)d_in[2], Qc, Kc, Vc, nQKV8, 512);
  convert4<<<512, 256, 0, stream>>>((const float*)d_in[4], (const float*)d_in[6],
                                    (const float*)d_in[8], (const float*)d_in[10],
                                    Wqc, Wkc, Wvc, Woc, nW8, 128);
  convert4<<<4, 256, 0, stream>>>((const float*)d_in[5], (const float*)d_in[7],
                                  (const float*)d_in[9], (const float*)d_in[11],
                                  bqc, bkc, bvc, boc, DMODEL / 8, 1);

  const int nwords = BATCH * SEQ * (SEQ / 64);  // 131072
  pack_mask<<<512, 256, 0, stream>>>(maskp, pm, nwords);

  qkv_proj<<<768, 256, 0, stream>>>(Qc, Kc, Vc, Wqc, Wkc, Wvc,
                                    bqc, bkc, bvc, Qb, Kb, Vb);

  attn<<<BATCH * NH * (SEQ / 128), 256, 0, stream>>>(Qb, Kb, Vb, pm, Ab);

  gemm_out<<<256, 256, 0, stream>>>(Ab, Woc, boc, out);
}